// Round 1
// baseline (293.809 us; speedup 1.0000x reference)
//
#include <hip/hip_runtime.h>
#include <hip/hip_bf16.h>
#include <stdint.h>

#define N_ROWS 4096
#define H_DIM  1024
#define V_SIZE 32000
#define IGNORE_INDEX (-100)

#define BV 128   // vocab tile (MFMA M dim)
#define BN 128   // row tile   (MFMA N dim)
#define BK 64    // K tile
#define N_TILES (N_ROWS / BN)   // 32
#define V_TILES (V_SIZE / BV)   // 250
#define K_TILES (H_DIM / BK)    // 16

typedef short short8 __attribute__((ext_vector_type(8)));
typedef float floatx4 __attribute__((ext_vector_type(4)));

static __device__ __forceinline__ unsigned short f2bf(float f) {
    uint32_t u = __float_as_uint(f);
    uint32_t r = (u + 0x7fffu + ((u >> 16) & 1u)) >> 16;
    return (unsigned short)r;
}
static __device__ __forceinline__ float bf2f(unsigned short b) {
    return __uint_as_float(((uint32_t)b) << 16);
}

static __device__ __forceinline__ void gload_lds16(const void* g, void* l) {
    __builtin_amdgcn_global_load_lds(
        (const __attribute__((address_space(1))) unsigned int*)g,
        (__attribute__((address_space(3))) unsigned int*)l,
        16 /*bytes*/, 0 /*offset*/, 0 /*aux*/);
}

// ---- K1: x fp32 -> bf16 ----------------------------------------------------
__global__ void k_convert_x(const float* __restrict__ x, unsigned short* __restrict__ xb) {
    int i = (blockIdx.x * blockDim.x + threadIdx.x) * 4;
    float4 v = *(const float4*)(x + i);
    ushort4 o;
    o.x = f2bf(v.x); o.y = f2bf(v.y); o.z = f2bf(v.z); o.w = f2bf(v.w);
    *(ushort4*)(xb + i) = o;
}

// ---- K2: W [H][V] fp32 -> Wt [V][H] bf16 (tiled transpose) -----------------
__global__ void k_transpose_w(const float* __restrict__ W, unsigned short* __restrict__ wt) {
    __shared__ unsigned short tile[32][33];
    int v0 = blockIdx.x * 32;
    int k0 = blockIdx.y * 32;
    int tx = threadIdx.x;   // 0..31
    int ty = threadIdx.y;   // 0..7
#pragma unroll
    for (int i = 0; i < 4; ++i) {
        int k = k0 + ty + i * 8;
        tile[ty + i * 8][tx] = f2bf(W[(size_t)k * V_SIZE + v0 + tx]);
    }
    __syncthreads();
#pragma unroll
    for (int i = 0; i < 4; ++i) {
        int v = v0 + ty + i * 8;
        wt[(size_t)v * H_DIM + k0 + tx] = tile[tx][ty + i * 8];
    }
}

// ---- K3: fused GEMM (Wt x xb^T) + exp + column-sum partials ----------------
// D[v][n] = sum_k Wt[v][k] * xb[n][k];  Spart[vt][n] = sum_{v in tile} exp(D)
__global__ __launch_bounds__(256, 2) void k_gemm_expsum(
    const unsigned short* __restrict__ wt,
    const unsigned short* __restrict__ xb,
    float* __restrict__ Spart)
{
    __shared__ unsigned short a_sm[BV * BK];  // Wt tile, swizzled rows
    __shared__ unsigned short b_sm[BN * BK];  // x  tile, swizzled rows
    __shared__ float red[2][BN];

    const int bid = blockIdx.x;
    const int nt = bid & (N_TILES - 1);
    const int vt = bid >> 5;
    const int v0 = vt * BV;
    const int n0 = nt * BN;

    const int t = threadIdx.x;
    const int lane = t & 63;
    const int w = t >> 6;       // wave 0..3
    const int wv = w >> 1;      // v half
    const int wn = w & 1;       // n half

    // staging geometry: 16KB tile = 16 chunks of 1KB; wave w owns chunks w*4..w*4+3
    // LDS linear (row, cb) holds global (row, cb ^ ((row&7)<<4))  [rule #21]
    const int srcColb = (((lane & 7) ^ (lane >> 3)) << 4);
    const char* aG = (const char*)wt + (size_t)v0 * H_DIM * 2;
    const char* bG = (const char*)xb + (size_t)n0 * H_DIM * 2;

    floatx4 acc[4][4] = {};

    for (int kt = 0; kt < K_TILES; ++kt) {
        const size_t kb = (size_t)kt * BK * 2;
#pragma unroll
        for (int c = 0; c < 4; ++c) {
            int row = w * 32 + c * 8 + (lane >> 3);
            gload_lds16(aG + (size_t)row * (H_DIM * 2) + kb + srcColb,
                        (char*)a_sm + (w * 4 + c) * 1024);
        }
#pragma unroll
        for (int c = 0; c < 4; ++c) {
            int row = w * 32 + c * 8 + (lane >> 3);
            gload_lds16(bG + (size_t)row * (H_DIM * 2) + kb + srcColb,
                        (char*)b_sm + (w * 4 + c) * 1024);
        }
        asm volatile("s_waitcnt vmcnt(0)" ::: "memory");
        __syncthreads();

#pragma unroll
        for (int ks = 0; ks < 2; ++ks) {
            const int koff = ks * 64 + ((lane >> 4) << 4);
            short8 af[4], bfr[4];
#pragma unroll
            for (int m = 0; m < 4; ++m) {
                int vr = wv * 64 + m * 16 + (lane & 15);
                int addr = vr * 128 + (koff ^ ((vr & 7) << 4));
                af[m] = *(const short8*)((const char*)a_sm + addr);
            }
#pragma unroll
            for (int n = 0; n < 4; ++n) {
                int nr = wn * 64 + n * 16 + (lane & 15);
                int addr = nr * 128 + (koff ^ ((nr & 7) << 4));
                bfr[n] = *(const short8*)((const char*)b_sm + addr);
            }
#pragma unroll
            for (int m = 0; m < 4; ++m)
#pragma unroll
                for (int n = 0; n < 4; ++n)
                    acc[m][n] = __builtin_amdgcn_mfma_f32_16x16x32_bf16(
                        af[m], bfr[n], acc[m][n], 0, 0, 0);
        }
        __syncthreads();
    }

    // epilogue: exp + column sums.  C/D map: col = lane&15 (n), row = (lane>>4)*4 + r (v)
    float csum[4];
#pragma unroll
    for (int nf = 0; nf < 4; ++nf) {
        float s = 0.f;
#pragma unroll
        for (int m = 0; m < 4; ++m)
#pragma unroll
            for (int r = 0; r < 4; ++r)
                s += __expf(acc[m][nf][r]);
        s += __shfl_xor(s, 16, 64);
        s += __shfl_xor(s, 32, 64);
        csum[nf] = s;
    }
    if ((lane >> 4) == 0) {
#pragma unroll
        for (int nf = 0; nf < 4; ++nf)
            red[wv][wn * 64 + nf * 16 + lane] = csum[nf];
    }
    __syncthreads();
    if (t < BN) {
        float S = red[0][t] + red[1][t];
        Spart[(size_t)vt * N_ROWS + n0 + t] = S;
    }
}

// ---- K4: target logits (bf16 dot, consistent with GEMM inputs) -------------
__global__ void k_tgt(const unsigned short* __restrict__ xb,
                      const unsigned short* __restrict__ wt,
                      const int* __restrict__ tgt,
                      float* __restrict__ tlog)
{
    int w = threadIdx.x >> 6;
    int lane = threadIdx.x & 63;
    int n = blockIdx.x * 4 + w;
    int tg = tgt[n];
    int ts = (tg == IGNORE_INDEX) ? 0 : tg;
    const unsigned short* xr = xb + (size_t)n * H_DIM;
    const unsigned short* wr = wt + (size_t)ts * H_DIM;
    float s = 0.f;
#pragma unroll
    for (int i = 0; i < H_DIM / 64; ++i) {
        int k = lane + i * 64;
        s += bf2f(xr[k]) * bf2f(wr[k]);
    }
#pragma unroll
    for (int off = 32; off; off >>= 1) s += __shfl_xor(s, off, 64);
    if (lane == 0) tlog[n] = s;
}

// ---- K5: per-row loss + block partials -------------------------------------
__global__ void k_rowloss(const float* __restrict__ Spart,
                          const float* __restrict__ tlog,
                          const int* __restrict__ tgt,
                          float* __restrict__ partials)
{
    int n = blockIdx.x * 256 + threadIdx.x;
    float S = 0.f;
    for (int vt2 = 0; vt2 < V_TILES; ++vt2)
        S += Spart[(size_t)vt2 * N_ROWS + n];
    float loss = 0.f;
    int tg = tgt[n];
    if (tg != IGNORE_INDEX) loss = logf(S) - tlog[n];

    __shared__ float sm[256];
    sm[threadIdx.x] = loss;
    __syncthreads();
    for (int s2 = 128; s2 > 0; s2 >>= 1) {
        if (threadIdx.x < s2) sm[threadIdx.x] += sm[threadIdx.x + s2];
        __syncthreads();
    }
    if (threadIdx.x == 0) partials[blockIdx.x] = sm[0];
}

__global__ void k_final(const float* __restrict__ partials, float* __restrict__ out) {
    if (threadIdx.x == 0) {
        float s = 0.f;
        for (int i = 0; i < 16; ++i) s += partials[i];
        out[0] = s;
    }
}

// ---- launch ----------------------------------------------------------------
extern "C" void kernel_launch(void* const* d_in, const int* in_sizes, int n_in,
                              void* d_out, int out_size, void* d_ws, size_t ws_size,
                              hipStream_t stream)
{
    const float* x = (const float*)d_in[0];
    const float* W = (const float*)d_in[1];
    const int* tgt = (const int*)d_in[2];
    float* out = (float*)d_out;

    char* ws = (char*)d_ws;
    size_t off = 0;
    unsigned short* xb = (unsigned short*)(ws + off); off += (size_t)N_ROWS * H_DIM * 2;
    unsigned short* wt = (unsigned short*)(ws + off); off += (size_t)V_SIZE * H_DIM * 2;
    float* Spart = (float*)(ws + off);                off += (size_t)V_TILES * N_ROWS * 4;
    float* tlog  = (float*)(ws + off);                off += (size_t)N_ROWS * 4;
    float* partials = (float*)(ws + off);             off += 64;

    k_convert_x<<<(N_ROWS * H_DIM / 4) / 256, 256, 0, stream>>>(x, xb);
    k_transpose_w<<<dim3(V_SIZE / 32, H_DIM / 32), dim3(32, 8), 0, stream>>>(W, wt);
    k_gemm_expsum<<<V_TILES * N_TILES, 256, 0, stream>>>(wt, xb, Spart);
    k_tgt<<<N_ROWS / 4, 256, 0, stream>>>(xb, wt, tgt, tlog);
    k_rowloss<<<16, 256, 0, stream>>>(Spart, tlog, tgt, partials);
    k_final<<<1, 64, 0, stream>>>(partials, out);
}